// Round 4
// baseline (11472.059 us; speedup 1.0000x reference)
//
#include <hip/hip_runtime.h>
#include <cmath>

#define SEQ   512
#define BATCH 64
#define DIN   1024
#define DH    1024

// ---------------------------------------------------------------------------
// Phase 1: x_proj = X @ W_ih^T + b_ih + b_hh  -> written into d_out[s][b][h]
// ---------------------------------------------------------------------------
__global__ __launch_bounds__(256) void proj_kernel(
    const float* __restrict__ X, const float* __restrict__ W,
    const float* __restrict__ b_ih, const float* __restrict__ b_hh,
    float* __restrict__ C) {
  __shared__ float As[64][17];
  __shared__ float Bs[64][17];
  const int m0 = blockIdx.x * 64;
  const int n0 = blockIdx.y * 64;
  const int tid = threadIdx.x;
  const int tm = tid >> 4;
  const int tn = tid & 15;
  const int lrow = tid >> 2;
  const int lk4  = (tid & 3) * 4;

  float acc[4][4];
#pragma unroll
  for (int i = 0; i < 4; ++i)
#pragma unroll
    for (int j = 0; j < 4; ++j) acc[i][j] = 0.f;

  for (int kt = 0; kt < DIN; kt += 16) {
    float4 av = *(const float4*)(X + (size_t)(m0 + lrow) * DIN + kt + lk4);
    float4 bv = *(const float4*)(W + (size_t)(n0 + lrow) * DIN + kt + lk4);
    __syncthreads();
    As[lrow][lk4 + 0] = av.x; As[lrow][lk4 + 1] = av.y;
    As[lrow][lk4 + 2] = av.z; As[lrow][lk4 + 3] = av.w;
    Bs[lrow][lk4 + 0] = bv.x; Bs[lrow][lk4 + 1] = bv.y;
    Bs[lrow][lk4 + 2] = bv.z; Bs[lrow][lk4 + 3] = bv.w;
    __syncthreads();
#pragma unroll
    for (int kk = 0; kk < 16; ++kk) {
      float a[4], b[4];
#pragma unroll
      for (int i = 0; i < 4; ++i) a[i] = As[tm * 4 + i][kk];
#pragma unroll
      for (int j = 0; j < 4; ++j) b[j] = Bs[tn * 4 + j][kk];
#pragma unroll
      for (int i = 0; i < 4; ++i)
#pragma unroll
        for (int j = 0; j < 4; ++j) acc[i][j] += a[i] * b[j];
    }
  }

#pragma unroll
  for (int j = 0; j < 4; ++j) {
    const int n = n0 + tn * 4 + j;
    const float bias = b_ih[n] + b_hh[n];
#pragma unroll
    for (int i = 0; i < 4; ++i) {
      const int m = m0 + tm * 4 + i;
      C[(size_t)m * DH + n] = acc[i][j] + bias;
    }
  }
}

// ---------------------------------------------------------------------------
// h0 -> transposed quad-packed layout: flat float4 index = k4*64 + b,
// holding h[b][4k4..4k4+3]. Coalesced; one-shot.
// ---------------------------------------------------------------------------
__global__ __launch_bounds__(256) void transpose_h0(
    const float* __restrict__ h0, float* __restrict__ hT) {
  const int idx = blockIdx.x * 256 + threadIdx.x;  // 0..16383
  const int k4 = idx >> 6;
  const int b = idx & 63;
  float4 v = *(const float4*)(h0 + (size_t)b * DH + (k4 << 2));
  ((float4*)hT)[idx] = v;
}

// ---------------------------------------------------------------------------
// Phase 2 step. Grid 512 blocks x 256 thr (2 blocks/CU, 2 waves/SIMD).
// Block owns 2 j-rows; wave wv handles k-quarter (256 k) of both rows.
// h from quad-packed transposed ping-pong (coalesced float4). W rows are
// wave-uniform -> scalar path; per-wave scalar footprint only 2 KB.
// 4-wave partials reduced through 2 KB LDS, then tanh + stores.
// ---------------------------------------------------------------------------
__global__ __launch_bounds__(256, 2) void rnn_step(
    const float* __restrict__ hTprev, float* __restrict__ hTnext,
    const float* __restrict__ W_hh, float* __restrict__ out, int t) {
  __shared__ float part[4][2][64];
  const int tid = threadIdx.x;
  const int b = tid & 63;
  const int wv = tid >> 6;  // k-quarter, wave-uniform
  const int j0 = __builtin_amdgcn_readfirstlane(blockIdx.x << 1);
  const float* __restrict__ w0 = W_hh + (size_t)j0 * DH + (wv << 8);
  const float* __restrict__ w1 = w0 + DH;
  const float4* __restrict__ hp = (const float4*)hTprev + ((size_t)wv << 12);

  float a0 = 0.f, a1 = 0.f, a2 = 0.f, a3 = 0.f;
#pragma unroll 8
  for (int k4 = 0; k4 < 64; ++k4) {
    float4 hv = hp[(k4 << 6) + b];
    const int k = k4 << 2;
    a0 = fmaf(w0[k + 0], hv.x, a0);
    a1 = fmaf(w0[k + 1], hv.y, a1);
    a0 = fmaf(w0[k + 2], hv.z, a0);
    a1 = fmaf(w0[k + 3], hv.w, a1);
    a2 = fmaf(w1[k + 0], hv.x, a2);
    a3 = fmaf(w1[k + 1], hv.y, a3);
    a2 = fmaf(w1[k + 2], hv.z, a2);
    a3 = fmaf(w1[k + 3], hv.w, a3);
  }
  part[wv][0][b] = a0 + a1;
  part[wv][1][b] = a2 + a3;
  __syncthreads();

  if (tid < 128) {
    const int jp = tid >> 6;  // 0..1
    const int bb = tid & 63;
    const float s = part[0][jp][bb] + part[1][jp][bb] +
                    part[2][jp][bb] + part[3][jp][bb];
    const int j = j0 + jp;
    const size_t oi = ((size_t)t * BATCH + bb) * DH + j;
    const float v = tanhf(out[oi] + s);
    out[oi] = v;
    // hTnext quad-packed: float offset = (k4*64 + b)*4 + (k&3), with k=j
    hTnext[((((size_t)(j >> 2)) << 6) + bb) * 4 + (j & 3)] = v;
    if (t == SEQ - 1) {
      out[(size_t)SEQ * BATCH * DH + (size_t)bb * DH + j] = v;
    }
  }
}

extern "C" void kernel_launch(void* const* d_in, const int* in_sizes, int n_in,
                              void* d_out, int out_size, void* d_ws,
                              size_t ws_size, hipStream_t stream) {
  const float* x    = (const float*)d_in[0];
  const float* h0   = (const float*)d_in[1];
  const float* W_ih = (const float*)d_in[2];
  const float* b_ih = (const float*)d_in[3];
  const float* W_hh = (const float*)d_in[4];
  const float* b_hh = (const float*)d_in[5];
  float* out = (float*)d_out;
  float* hA = (float*)d_ws;              // 256 KB
  float* hB = hA + (size_t)DH * BATCH;   // 256 KB

  // Phase 1: input projection + both biases -> d_out[s][b][h]
  hipLaunchKernelGGL(proj_kernel, dim3(512, 16), dim3(256), 0, stream,
                     x, W_ih, b_ih, b_hh, out);

  // h0 -> transposed quad-packed buffer A
  hipLaunchKernelGGL(transpose_h0, dim3(64), dim3(256), 0, stream, h0, hA);

  // Phase 2: one launch per step, ping-pong hT buffers
  for (int t = 0; t < SEQ; ++t) {
    const float* src = (t & 1) ? hB : hA;
    float* dst = (t & 1) ? hA : hB;
    hipLaunchKernelGGL(rnn_step, dim3(512), dim3(256), 0, stream,
                       src, dst, W_hh, out, t);
  }
}